// Round 1
// baseline (1028.176 us; speedup 1.0000x reference)
//
#include <hip/hip_runtime.h>
#include <math.h>

#define TOK 9232      // B*N = 16*577
#define EMB 1024
#define NQKV 3072
#define FFD 4096
#define NSEQ 577

typedef __bf16 bf16x8 __attribute__((ext_vector_type(8)));
typedef float f32x4 __attribute__((ext_vector_type(4)));
typedef unsigned short ushort8 __attribute__((ext_vector_type(8)));
typedef unsigned short ushort4v __attribute__((ext_vector_type(4)));

__device__ __forceinline__ unsigned short f2bf(float f) {
    unsigned int u = __builtin_bit_cast(unsigned int, f);
    u = (u + 0x7fffu + ((u >> 16) & 1u)) >> 16;
    return (unsigned short)u;
}
__device__ __forceinline__ float bf2f(unsigned short s) {
    unsigned int u = ((unsigned int)s) << 16;
    return __builtin_bit_cast(float, u);
}
__device__ __forceinline__ float gelu_exact(float x) {
    return 0.5f * x * (1.0f + erff(x * 0.70710678118654752f));
}

// ---------- weight conversion / packing ----------
__global__ void k_f32_to_bf16(const float* __restrict__ in, unsigned short* __restrict__ out, int n) {
    int i = blockIdx.x * 256 + threadIdx.x;
    if (i < n) out[i] = f2bf(in[i]);
}
// lora_B [4][3072][16] -> Bcat[o][x*16+r]
__global__ void k_pack_bcat(const float* __restrict__ Bw, unsigned short* __restrict__ out) {
    int i = blockIdx.x * 256 + threadIdx.x;
    if (i >= 4 * 3072 * 16) return;
    int x = i / (3072 * 16);
    int rem = i - x * (3072 * 16);
    int o = rem >> 4;
    int r = rem & 15;
    out[o * 64 + x * 16 + r] = f2bf(Bw[i]);
}
// ad_up_w [4][1024][64] -> U[o][x*64+h]
__global__ void k_pack_u(const float* __restrict__ Uw, unsigned short* __restrict__ out) {
    int i = blockIdx.x * 256 + threadIdx.x;
    if (i >= 4 * 1024 * 64) return;
    int x = i >> 16;
    int o = (i >> 6) & 1023;
    int h = i & 63;
    out[o * 256 + x * 64 + h] = f2bf(Uw[i]);
}

// ---------- layernorm (fp32 in -> bf16 out), one block per token ----------
__global__ __launch_bounds__(256) void k_layernorm(const float* __restrict__ x,
                                                   const float* __restrict__ g,
                                                   const float* __restrict__ b,
                                                   unsigned short* __restrict__ out) {
    int t = blockIdx.x;
    int tid = threadIdx.x;
    const float* xp = x + (size_t)t * EMB;
    float4 v = ((const float4*)xp)[tid];
    float s = v.x + v.y + v.z + v.w;
    float sq = v.x * v.x + v.y * v.y + v.z * v.z + v.w * v.w;
    #pragma unroll
    for (int off = 32; off > 0; off >>= 1) {
        s += __shfl_down(s, off);
        sq += __shfl_down(sq, off);
    }
    __shared__ float red[8];
    if ((tid & 63) == 0) { red[tid >> 6] = s; red[(tid >> 6) + 4] = sq; }
    __syncthreads();
    float S = red[0] + red[1] + red[2] + red[3];
    float SQ = red[4] + red[5] + red[6] + red[7];
    float mean = S * (1.0f / EMB);
    float var = SQ * (1.0f / EMB) - mean * mean;
    float rstd = rsqrtf(var + 1e-6f);
    float4 gv = ((const float4*)g)[tid];
    float4 bv = ((const float4*)b)[tid];
    ushort4v o;
    o[0] = f2bf((v.x - mean) * rstd * gv.x + bv.x);
    o[1] = f2bf((v.y - mean) * rstd * gv.y + bv.y);
    o[2] = f2bf((v.z - mean) * rstd * gv.z + bv.z);
    o[3] = f2bf((v.w - mean) * rstd * gv.w + bv.w);
    ((ushort4v*)(out + (size_t)t * EMB))[tid] = o;
}

// ---------- gate softmax (4 experts), one block per token ----------
__global__ __launch_bounds__(256) void k_gates(const unsigned short* __restrict__ act,
                                               const float* __restrict__ gw,
                                               float* __restrict__ out) {
    int t = blockIdx.x;
    int tid = threadIdx.x;
    ushort4v av = *(const ushort4v*)(act + (size_t)t * EMB + tid * 4);
    float a0 = bf2f(av[0]), a1 = bf2f(av[1]), a2 = bf2f(av[2]), a3 = bf2f(av[3]);
    float p[4];
    #pragma unroll
    for (int x = 0; x < 4; ++x) {
        float4 g = ((const float4*)(gw + x * EMB))[tid];
        p[x] = a0 * g.x + a1 * g.y + a2 * g.z + a3 * g.w;
    }
    #pragma unroll
    for (int off = 32; off > 0; off >>= 1) {
        #pragma unroll
        for (int x = 0; x < 4; ++x) p[x] += __shfl_down(p[x], off);
    }
    __shared__ float red[4][4];
    if ((tid & 63) == 0) {
        #pragma unroll
        for (int x = 0; x < 4; ++x) red[tid >> 6][x] = p[x];
    }
    __syncthreads();
    if (tid == 0) {
        float l[4];
        #pragma unroll
        for (int x = 0; x < 4; ++x) l[x] = red[0][x] + red[1][x] + red[2][x] + red[3][x];
        float m = fmaxf(fmaxf(l[0], l[1]), fmaxf(l[2], l[3]));
        float e[4], ssum = 0.f;
        #pragma unroll
        for (int x = 0; x < 4; ++x) { e[x] = expf(l[x] - m); ssum += e[x]; }
        float inv = 1.0f / ssum;
        #pragma unroll
        for (int x = 0; x < 4; ++x) out[t * 4 + x] = e[x] * inv;
    }
}

// hw[t][x*16+r] = gates[t][x] * lora_h[t][x*16+r]  (bf16)
__global__ void k_make_hw(const float* __restrict__ gates, const float* __restrict__ lh,
                          unsigned short* __restrict__ hw) {
    int i = blockIdx.x * 256 + threadIdx.x;
    if (i >= TOK * 64) return;
    int t = i >> 6;
    int j = i & 63;
    hw[i] = f2bf(gates[t * 4 + (j >> 4)] * lh[i]);
}

// ahw[t][x*64+h] = ag[t][x] * gelu(ahpre[t][x*64+h])  (bf16)
__global__ void k_make_ahw(const float* __restrict__ ag, const float* __restrict__ ahpre,
                           unsigned short* __restrict__ ahw) {
    int i = blockIdx.x * 256 + threadIdx.x;
    if (i >= TOK * 256) return;
    int t = i >> 8;
    int j = i & 255;
    ahw[i] = f2bf(ag[t * 4 + (j >> 6)] * gelu_exact(ahpre[i]));
}

// tok2[t][o] += sum_x ag[t][x] * ad_up_b[x][o]
__global__ __launch_bounds__(256) void k_adbias(const float* __restrict__ ag,
                                                const float* __restrict__ upb,
                                                float* __restrict__ tok2) {
    int t = blockIdx.x;
    int tid = threadIdx.x;
    float g0 = ag[t * 4 + 0], g1 = ag[t * 4 + 1], g2 = ag[t * 4 + 2], g3 = ag[t * 4 + 3];
    float4 b0 = ((const float4*)(upb + 0 * EMB))[tid];
    float4 b1 = ((const float4*)(upb + 1 * EMB))[tid];
    float4 b2 = ((const float4*)(upb + 2 * EMB))[tid];
    float4 b3 = ((const float4*)(upb + 3 * EMB))[tid];
    float4 r = ((float4*)(tok2 + (size_t)t * EMB))[tid];
    r.x += g0 * b0.x + g1 * b1.x + g2 * b2.x + g3 * b3.x;
    r.y += g0 * b0.y + g1 * b1.y + g2 * b2.y + g3 * b3.y;
    r.z += g0 * b0.z + g1 * b1.z + g2 * b2.z + g3 * b3.z;
    r.w += g0 * b0.w + g1 * b1.w + g2 * b2.w + g3 * b3.w;
    ((float4*)(tok2 + (size_t)t * EMB))[tid] = r;
}

// ---------- MFMA GEMM: C[M,N] = A[M,K] @ W[N,K]^T (+ A2@W2^T) (+bias) (gelu?) (+resid) ----------
// 128x128 block tile, 4 waves of 64x64, BK=32.
template<bool GELU, bool BF16OUT>
__global__ __launch_bounds__(256) void k_gemm(
    const unsigned short* __restrict__ A, const unsigned short* __restrict__ W,
    int M, int N, int K,
    const unsigned short* __restrict__ A2, const unsigned short* __restrict__ W2, int K2,
    const float* __restrict__ bias, const float* __restrict__ resid,
    void* __restrict__ Cout, int ldc)
{
    __shared__ unsigned short As[128][40];
    __shared__ unsigned short Ws[128][40];
    int tid = threadIdx.x;
    int bm128 = blockIdx.x * 128;
    int bn128 = blockIdx.y * 128;
    int l = tid & 63, w = tid >> 6;
    int wr = w >> 1, wc = w & 1;
    int lr = l & 15, lk = (l >> 4) * 8;

    f32x4 acc[4][4];
    #pragma unroll
    for (int m = 0; m < 4; ++m)
        #pragma unroll
        for (int n = 0; n < 4; ++n) acc[m][n] = (f32x4){0.f, 0.f, 0.f, 0.f};

    auto kloop = [&](const unsigned short* __restrict__ Ap,
                     const unsigned short* __restrict__ Wp, int Kc) {
        for (int k0 = 0; k0 < Kc; k0 += 32) {
            #pragma unroll
            for (int p = 0; p < 2; ++p) {
                int idx = (p << 8) + tid;
                int row = idx >> 2;
                int kk = (idx & 3) << 3;
                int ra = bm128 + row;
                ushort8 va = {};
                if (ra < M) va = *(const ushort8*)(Ap + (size_t)ra * Kc + k0 + kk);
                *(ushort8*)&As[row][kk] = va;
                int rb = bn128 + row;
                ushort8 vb = {};
                if (rb < N) vb = *(const ushort8*)(Wp + (size_t)rb * Kc + k0 + kk);
                *(ushort8*)&Ws[row][kk] = vb;
            }
            __syncthreads();
            bf16x8 af[4], bfr[4];
            #pragma unroll
            for (int m = 0; m < 4; ++m) af[m] = *(const bf16x8*)&As[wr * 64 + m * 16 + lr][lk];
            #pragma unroll
            for (int n = 0; n < 4; ++n) bfr[n] = *(const bf16x8*)&Ws[wc * 64 + n * 16 + lr][lk];
            #pragma unroll
            for (int m = 0; m < 4; ++m)
                #pragma unroll
                for (int n = 0; n < 4; ++n)
                    acc[m][n] = __builtin_amdgcn_mfma_f32_16x16x32_bf16(af[m], bfr[n], acc[m][n], 0, 0, 0);
            __syncthreads();
        }
    };
    kloop(A, W, K);
    if (A2) kloop(A2, W2, K2);

    int rb0 = bm128 + wr * 64;
    int cb0 = bn128 + wc * 64;
    #pragma unroll
    for (int n = 0; n < 4; ++n) {
        int col = cb0 + n * 16 + lr;
        if (col >= N) continue;
        float bv = bias ? bias[col] : 0.0f;
        #pragma unroll
        for (int m = 0; m < 4; ++m) {
            #pragma unroll
            for (int r = 0; r < 4; ++r) {
                int row = rb0 + m * 16 + (l >> 4) * 4 + r;
                if (row >= M) continue;
                float c = acc[m][n][r] + bv;
                if (GELU) c = gelu_exact(c);
                if (resid) c += resid[(size_t)row * ldc + col];
                if (BF16OUT) ((unsigned short*)Cout)[(size_t)row * ldc + col] = f2bf(c);
                else ((float*)Cout)[(size_t)row * ldc + col] = c;
            }
        }
    }
}

// ---------- flash attention: one block per (b*h, 64-row q tile) ----------
__global__ __launch_bounds__(256) void k_attn(const unsigned short* __restrict__ qkv,
                                              unsigned short* __restrict__ ctx) {
    int bh = blockIdx.x;
    int qt = blockIdx.y;
    int b = bh >> 4, h = bh & 15;
    int tid = threadIdx.x;
    int l = tid & 63;
    int w = tid >> 6;
    int lr = l & 15;
    int lk = (l >> 4) * 8;

    __shared__ unsigned short Qs[64][72];
    __shared__ unsigned short Ks[64][72];
    __shared__ unsigned short Vt[64][72];
    __shared__ unsigned short Ps[64][72];

    const size_t base = (size_t)b * NSEQ * NQKV + (size_t)h * 64;
    int q0 = qt * 64;

    {   // stage Q, pre-scaled by HD^-0.5 = 0.125 (exact pow2)
        int row = tid >> 2, ds = (tid & 3) * 16;
        int qrow = q0 + row;
        if (qrow < NSEQ) {
            const unsigned short* src = qkv + base + (size_t)qrow * NQKV + ds;
            #pragma unroll
            for (int j = 0; j < 16; ++j) Qs[row][ds + j] = f2bf(bf2f(src[j]) * 0.125f);
        } else {
            #pragma unroll
            for (int j = 0; j < 16; ++j) Qs[row][ds + j] = 0;
        }
    }

    float m_run[4], l_run[4];
    f32x4 o[4];
    #pragma unroll
    for (int r = 0; r < 4; ++r) { m_run[r] = -1e30f; l_run[r] = 0.0f; }
    #pragma unroll
    for (int n = 0; n < 4; ++n) o[n] = (f32x4){0.f, 0.f, 0.f, 0.f};

    for (int kt = 0; kt < 10; ++kt) {
        __syncthreads();
        {   // stage K (row-major) and V (transposed) tiles
            int row = tid >> 2, ds = (tid & 3) * 16;
            int key = kt * 64 + row;
            if (key < NSEQ) {
                const unsigned short* ksrc = qkv + base + (size_t)key * NQKV + 1024 + ds;
                *(ushort8*)&Ks[row][ds] = *(const ushort8*)ksrc;
                *(ushort8*)&Ks[row][ds + 8] = *(const ushort8*)(ksrc + 8);
                const unsigned short* vsrc = qkv + base + (size_t)key * NQKV + 2048 + ds;
                #pragma unroll
                for (int j = 0; j < 16; ++j) Vt[ds + j][row] = vsrc[j];
            } else {
                ushort8 z = {};
                *(ushort8*)&Ks[row][ds] = z;
                *(ushort8*)&Ks[row][ds + 8] = z;
                #pragma unroll
                for (int j = 0; j < 16; ++j) Vt[ds + j][row] = 0;
            }
        }
        __syncthreads();

        // S = Q @ K^T  (each wave: 16 q rows x 64 keys)
        f32x4 s[4];
        #pragma unroll
        for (int n = 0; n < 4; ++n) s[n] = (f32x4){0.f, 0.f, 0.f, 0.f};
        #pragma unroll
        for (int ks = 0; ks < 2; ++ks) {
            bf16x8 qa = *(const bf16x8*)&Qs[w * 16 + lr][ks * 32 + lk];
            #pragma unroll
            for (int n = 0; n < 4; ++n) {
                bf16x8 kb = *(const bf16x8*)&Ks[n * 16 + lr][ks * 32 + lk];
                s[n] = __builtin_amdgcn_mfma_f32_16x16x32_bf16(qa, kb, s[n], 0, 0, 0);
            }
        }
        // mask invalid keys
        #pragma unroll
        for (int n = 0; n < 4; ++n) {
            int col = kt * 64 + n * 16 + lr;
            if (col >= NSEQ) {
                #pragma unroll
                for (int r = 0; r < 4; ++r) s[n][r] = -1e30f;
            }
        }
        // online softmax (rows live across 16 lanes; xor-reduce within group)
        float tmax[4];
        #pragma unroll
        for (int r = 0; r < 4; ++r)
            tmax[r] = fmaxf(fmaxf(s[0][r], s[1][r]), fmaxf(s[2][r], s[3][r]));
        #pragma unroll
        for (int off = 1; off < 16; off <<= 1) {
            #pragma unroll
            for (int r = 0; r < 4; ++r) tmax[r] = fmaxf(tmax[r], __shfl_xor(tmax[r], off));
        }
        float alpha[4], rs[4];
        #pragma unroll
        for (int r = 0; r < 4; ++r) {
            float mn = fmaxf(m_run[r], tmax[r]);
            alpha[r] = __expf(m_run[r] - mn);
            m_run[r] = mn;
            rs[r] = 0.0f;
        }
        #pragma unroll
        for (int n = 0; n < 4; ++n) {
            #pragma unroll
            for (int r = 0; r < 4; ++r) {
                float p = __expf(s[n][r] - m_run[r]);
                s[n][r] = p;
                rs[r] += p;
            }
        }
        #pragma unroll
        for (int off = 1; off < 16; off <<= 1) {
            #pragma unroll
            for (int r = 0; r < 4; ++r) rs[r] += __shfl_xor(rs[r], off);
        }
        #pragma unroll
        for (int r = 0; r < 4; ++r) l_run[r] = l_run[r] * alpha[r] + rs[r];
        #pragma unroll
        for (int n = 0; n < 4; ++n) {
            #pragma unroll
            for (int r = 0; r < 4; ++r) o[n][r] *= alpha[r];
        }
        // P -> LDS (bf16), then O += P @ V
        #pragma unroll
        for (int n = 0; n < 4; ++n) {
            #pragma unroll
            for (int r = 0; r < 4; ++r)
                Ps[w * 16 + (l >> 4) * 4 + r][n * 16 + lr] = f2bf(s[n][r]);
        }
        __syncthreads();
        #pragma unroll
        for (int ks = 0; ks < 2; ++ks) {
            bf16x8 pa = *(const bf16x8*)&Ps[w * 16 + lr][ks * 32 + lk];
            #pragma unroll
            for (int n = 0; n < 4; ++n) {
                bf16x8 vb = *(const bf16x8*)&Vt[n * 16 + lr][ks * 32 + lk];
                o[n] = __builtin_amdgcn_mfma_f32_16x16x32_bf16(pa, vb, o[n], 0, 0, 0);
            }
        }
    }
    #pragma unroll
    for (int r = 0; r < 4; ++r) {
        int qrow = q0 + w * 16 + (l >> 4) * 4 + r;
        if (qrow < NSEQ) {
            float inv = (l_run[r] > 0.f) ? 1.0f / l_run[r] : 0.0f;
            #pragma unroll
            for (int n = 0; n < 4; ++n)
                ctx[((size_t)b * NSEQ + qrow) * EMB + h * 64 + n * 16 + lr] = f2bf(o[n][r] * inv);
        }
    }
}

extern "C" void kernel_launch(void* const* d_in, const int* in_sizes, int n_in,
                              void* d_out, int out_size, void* d_ws, size_t ws_size,
                              hipStream_t stream) {
    const float* tokens      = (const float*)d_in[0];
    const float* ln1_g       = (const float*)d_in[1];
    const float* ln1_b       = (const float*)d_in[2];
    const float* qkv_w       = (const float*)d_in[3];
    const float* qkv_b       = (const float*)d_in[4];
    const float* proj_w      = (const float*)d_in[5];
    const float* proj_b      = (const float*)d_in[6];
    const float* lora_gate_w = (const float*)d_in[7];
    const float* lora_A      = (const float*)d_in[8];
    const float* lora_B      = (const float*)d_in[9];
    const float* ln2_g       = (const float*)d_in[10];
    const float* ln2_b       = (const float*)d_in[11];
    const float* fc1_w       = (const float*)d_in[12];
    const float* fc1_b       = (const float*)d_in[13];
    const float* fc2_w       = (const float*)d_in[14];
    const float* fc2_b       = (const float*)d_in[15];
    const float* ad_gate_w   = (const float*)d_in[16];
    const float* ad_down_w   = (const float*)d_in[17];
    const float* ad_down_b   = (const float*)d_in[18];
    const float* ad_up_w     = (const float*)d_in[19];
    const float* ad_up_b     = (const float*)d_in[20];

    char* ws = (char*)d_ws;
    size_t off = 0;
    auto alloc = [&](size_t bytes) -> void* {
        void* p = ws + off;
        off += (bytes + 255) & ~(size_t)255;
        return p;
    };

    unsigned short* w_qkv  = (unsigned short*)alloc((size_t)NQKV * EMB * 2);
    unsigned short* w_proj = (unsigned short*)alloc((size_t)EMB * EMB * 2);
    unsigned short* w_fc1  = (unsigned short*)alloc((size_t)FFD * EMB * 2);
    unsigned short* w_fc2  = (unsigned short*)alloc((size_t)EMB * FFD * 2);
    unsigned short* w_acat = (unsigned short*)alloc((size_t)64 * EMB * 2);
    unsigned short* w_bcat = (unsigned short*)alloc((size_t)NQKV * 64 * 2);
    unsigned short* w_dcat = (unsigned short*)alloc((size_t)256 * EMB * 2);
    unsigned short* w_u    = (unsigned short*)alloc((size_t)EMB * 256 * 2);

    unsigned short* u1 = (unsigned short*)alloc((size_t)TOK * EMB * 2);  // normed -> mlpin
    char*           u2 = (char*)alloc((size_t)TOK * EMB * 2);            // ctx -> {ahpre, ahw}
    unsigned short* u3 = (unsigned short*)alloc((size_t)TOK * FFD * 2);  // qkv -> h1
    float* tok2   = (float*)alloc((size_t)TOK * EMB * 4);
    float* lora_h = (float*)alloc((size_t)TOK * 64 * 4);
    unsigned short* hw = (unsigned short*)alloc((size_t)TOK * 64 * 2);
    float* gates = (float*)alloc((size_t)TOK * 4 * 4);
    float* ag    = (float*)alloc((size_t)TOK * 4 * 4);

    unsigned short* normed = u1;
    unsigned short* mlpin  = u1;
    unsigned short* ctx    = (unsigned short*)u2;
    float*          ahpre  = (float*)u2;
    unsigned short* ahw    = (unsigned short*)(u2 + (size_t)TOK * 256 * 4);
    unsigned short* qkv    = u3;
    unsigned short* h1     = u3;

    // ---- weight conversion / packing ----
    k_f32_to_bf16<<<(NQKV * EMB + 255) / 256, 256, 0, stream>>>(qkv_w, w_qkv, NQKV * EMB);
    k_f32_to_bf16<<<(EMB * EMB + 255) / 256, 256, 0, stream>>>(proj_w, w_proj, EMB * EMB);
    k_f32_to_bf16<<<(FFD * EMB + 255) / 256, 256, 0, stream>>>(fc1_w, w_fc1, FFD * EMB);
    k_f32_to_bf16<<<(EMB * FFD + 255) / 256, 256, 0, stream>>>(fc2_w, w_fc2, EMB * FFD);
    k_f32_to_bf16<<<(64 * EMB + 255) / 256, 256, 0, stream>>>(lora_A, w_acat, 64 * EMB);
    k_pack_bcat<<<(NQKV * 64 + 255) / 256, 256, 0, stream>>>(lora_B, w_bcat);
    k_f32_to_bf16<<<(256 * EMB + 255) / 256, 256, 0, stream>>>(ad_down_w, w_dcat, 256 * EMB);
    k_pack_u<<<(EMB * 256 + 255) / 256, 256, 0, stream>>>(ad_up_w, w_u);

    // ---- forward ----
    k_layernorm<<<TOK, 256, 0, stream>>>(tokens, ln1_g, ln1_b, normed);
    k_gates<<<TOK, 256, 0, stream>>>(normed, lora_gate_w, gates);
    k_gemm<false, false><<<dim3(73, 1), 256, 0, stream>>>(
        normed, w_acat, TOK, 64, EMB, nullptr, nullptr, 0, nullptr, nullptr, lora_h, 64);
    k_make_hw<<<(TOK * 64 + 255) / 256, 256, 0, stream>>>(gates, lora_h, hw);
    k_gemm<false, true><<<dim3(73, 24), 256, 0, stream>>>(
        normed, w_qkv, TOK, NQKV, EMB, hw, w_bcat, 64, qkv_b, nullptr, qkv, NQKV);
    k_attn<<<dim3(256, 10), 256, 0, stream>>>(qkv, ctx);
    k_gemm<false, false><<<dim3(73, 8), 256, 0, stream>>>(
        ctx, w_proj, TOK, EMB, EMB, nullptr, nullptr, 0, proj_b, tokens, tok2, EMB);
    k_layernorm<<<TOK, 256, 0, stream>>>(tok2, ln2_g, ln2_b, mlpin);
    k_gates<<<TOK, 256, 0, stream>>>(mlpin, ad_gate_w, ag);
    k_gemm<false, false><<<dim3(73, 2), 256, 0, stream>>>(
        mlpin, w_dcat, TOK, 256, EMB, nullptr, nullptr, 0, ad_down_b, nullptr, ahpre, 256);
    k_make_ahw<<<(TOK * 256 + 255) / 256, 256, 0, stream>>>(ag, ahpre, ahw);
    k_adbias<<<TOK, 256, 0, stream>>>(ag, ad_up_b, tok2);
    k_gemm<true, true><<<dim3(73, 32), 256, 0, stream>>>(
        mlpin, w_fc1, TOK, FFD, EMB, nullptr, nullptr, 0, fc1_b, nullptr, h1, FFD);
    k_gemm<false, false><<<dim3(73, 8), 256, 0, stream>>>(
        h1, w_fc2, TOK, EMB, FFD, ahw, w_u, 256, fc2_b, tok2, d_out, EMB);
}

// Round 2
// 785.649 us; speedup vs baseline: 1.3087x; 1.3087x over previous
//
#include <hip/hip_runtime.h>
#include <math.h>

#define TOK 9232      // B*N = 16*577
#define EMB 1024
#define NQKV 3072
#define FFD 4096
#define NSEQ 577

typedef __bf16 bf16x8 __attribute__((ext_vector_type(8)));
typedef float f32x4 __attribute__((ext_vector_type(4)));
typedef unsigned short ushort8 __attribute__((ext_vector_type(8)));
typedef unsigned short ushort4v __attribute__((ext_vector_type(4)));

typedef __attribute__((address_space(3))) unsigned int lds_u32_t;
typedef const __attribute__((address_space(1))) unsigned int glob_u32_t;

__device__ __forceinline__ void async16(void* lds, const void* g) {
    __builtin_amdgcn_global_load_lds((glob_u32_t*)g, (lds_u32_t*)lds, 16, 0, 0);
}

__device__ __forceinline__ unsigned short f2bf(float f) {
    unsigned int u = __builtin_bit_cast(unsigned int, f);
    u = (u + 0x7fffu + ((u >> 16) & 1u)) >> 16;
    return (unsigned short)u;
}
__device__ __forceinline__ float bf2f(unsigned short s) {
    unsigned int u = ((unsigned int)s) << 16;
    return __builtin_bit_cast(float, u);
}
__device__ __forceinline__ float gelu_exact(float x) {
    return 0.5f * x * (1.0f + erff(x * 0.70710678118654752f));
}

// ---------- weight conversion / packing ----------
__global__ void k_f32_to_bf16(const float* __restrict__ in, unsigned short* __restrict__ out, int n) {
    int i = blockIdx.x * 256 + threadIdx.x;
    if (i < n) out[i] = f2bf(in[i]);
}
// lora_B [4][3072][16] -> Bcat[o][x*16+r]
__global__ void k_pack_bcat(const float* __restrict__ Bw, unsigned short* __restrict__ out) {
    int i = blockIdx.x * 256 + threadIdx.x;
    if (i >= 4 * 3072 * 16) return;
    int x = i / (3072 * 16);
    int rem = i - x * (3072 * 16);
    int o = rem >> 4;
    int r = rem & 15;
    out[o * 64 + x * 16 + r] = f2bf(Bw[i]);
}
// ad_up_w [4][1024][64] -> U[o][x*64+h]
__global__ void k_pack_u(const float* __restrict__ Uw, unsigned short* __restrict__ out) {
    int i = blockIdx.x * 256 + threadIdx.x;
    if (i >= 4 * 1024 * 64) return;
    int x = i >> 16;
    int o = (i >> 6) & 1023;
    int h = i & 63;
    out[o * 256 + x * 64 + h] = f2bf(Uw[i]);
}

// ---------- fused layernorm + 4-expert gate softmax, one block per token ----------
__global__ __launch_bounds__(256) void k_ln_gates(const float* __restrict__ x,
                                                  const float* __restrict__ g,
                                                  const float* __restrict__ b,
                                                  const float* __restrict__ gw,
                                                  unsigned short* __restrict__ out,
                                                  float* __restrict__ gates) {
    int t = blockIdx.x;
    int tid = threadIdx.x;
    const float* xp = x + (size_t)t * EMB;
    float4 v = ((const float4*)xp)[tid];
    float s = v.x + v.y + v.z + v.w;
    float sq = v.x * v.x + v.y * v.y + v.z * v.z + v.w * v.w;
    #pragma unroll
    for (int off = 32; off > 0; off >>= 1) {
        s += __shfl_down(s, off);
        sq += __shfl_down(sq, off);
    }
    __shared__ float red[8];
    if ((tid & 63) == 0) { red[tid >> 6] = s; red[(tid >> 6) + 4] = sq; }
    __syncthreads();
    float S = red[0] + red[1] + red[2] + red[3];
    float SQ = red[4] + red[5] + red[6] + red[7];
    float mean = S * (1.0f / EMB);
    float var = SQ * (1.0f / EMB) - mean * mean;
    float rstd = rsqrtf(var + 1e-6f);
    float4 gv = ((const float4*)g)[tid];
    float4 bv = ((const float4*)b)[tid];
    float n0 = (v.x - mean) * rstd * gv.x + bv.x;
    float n1 = (v.y - mean) * rstd * gv.y + bv.y;
    float n2 = (v.z - mean) * rstd * gv.z + bv.z;
    float n3 = (v.w - mean) * rstd * gv.w + bv.w;
    ushort4v o;
    o[0] = f2bf(n0); o[1] = f2bf(n1); o[2] = f2bf(n2); o[3] = f2bf(n3);
    ((ushort4v*)(out + (size_t)t * EMB))[tid] = o;
    // gate logits
    float p[4];
    #pragma unroll
    for (int xx = 0; xx < 4; ++xx) {
        float4 gr = ((const float4*)(gw + xx * EMB))[tid];
        p[xx] = n0 * gr.x + n1 * gr.y + n2 * gr.z + n3 * gr.w;
    }
    #pragma unroll
    for (int off = 32; off > 0; off >>= 1) {
        #pragma unroll
        for (int xx = 0; xx < 4; ++xx) p[xx] += __shfl_down(p[xx], off);
    }
    __shared__ float red2[4][4];
    if ((tid & 63) == 0) {
        #pragma unroll
        for (int xx = 0; xx < 4; ++xx) red2[tid >> 6][xx] = p[xx];
    }
    __syncthreads();
    if (tid == 0) {
        float l[4];
        #pragma unroll
        for (int xx = 0; xx < 4; ++xx) l[xx] = red2[0][xx] + red2[1][xx] + red2[2][xx] + red2[3][xx];
        float m = fmaxf(fmaxf(l[0], l[1]), fmaxf(l[2], l[3]));
        float e[4], ssum = 0.f;
        #pragma unroll
        for (int xx = 0; xx < 4; ++xx) { e[xx] = expf(l[xx] - m); ssum += e[xx]; }
        float inv = 1.0f / ssum;
        #pragma unroll
        for (int xx = 0; xx < 4; ++xx) gates[t * 4 + xx] = e[xx] * inv;
    }
}

// hw[t][x*16+r] = gates[t][x] * lora_h[t][x*16+r]  (bf16)
__global__ void k_make_hw(const float* __restrict__ gates, const float* __restrict__ lh,
                          unsigned short* __restrict__ hw) {
    int i = blockIdx.x * 256 + threadIdx.x;
    if (i >= TOK * 64) return;
    int t = i >> 6;
    int j = i & 63;
    hw[i] = f2bf(gates[t * 4 + (j >> 4)] * lh[i]);
}

// ahw[t][x*64+h] = ag[t][x] * gelu(ahpre[t][x*64+h])  (bf16)
__global__ void k_make_ahw(const float* __restrict__ ag, const float* __restrict__ ahpre,
                           unsigned short* __restrict__ ahw) {
    int i = blockIdx.x * 256 + threadIdx.x;
    if (i >= TOK * 256) return;
    int t = i >> 8;
    int j = i & 255;
    ahw[i] = f2bf(ag[t * 4 + (j >> 6)] * gelu_exact(ahpre[i]));
}

// tok2[t][o] += sum_x ag[t][x] * ad_up_b[x][o]
__global__ __launch_bounds__(256) void k_adbias(const float* __restrict__ ag,
                                                const float* __restrict__ upb,
                                                float* __restrict__ tok2) {
    int t = blockIdx.x;
    int tid = threadIdx.x;
    float g0 = ag[t * 4 + 0], g1 = ag[t * 4 + 1], g2 = ag[t * 4 + 2], g3 = ag[t * 4 + 3];
    float4 b0 = ((const float4*)(upb + 0 * EMB))[tid];
    float4 b1 = ((const float4*)(upb + 1 * EMB))[tid];
    float4 b2 = ((const float4*)(upb + 2 * EMB))[tid];
    float4 b3 = ((const float4*)(upb + 3 * EMB))[tid];
    float4 r = ((float4*)(tok2 + (size_t)t * EMB))[tid];
    r.x += g0 * b0.x + g1 * b1.x + g2 * b2.x + g3 * b3.x;
    r.y += g0 * b0.y + g1 * b1.y + g2 * b2.y + g3 * b3.y;
    r.z += g0 * b0.z + g1 * b1.z + g2 * b2.z + g3 * b3.z;
    r.w += g0 * b0.w + g1 * b1.w + g2 * b2.w + g3 * b3.w;
    ((float4*)(tok2 + (size_t)t * EMB))[tid] = r;
}

// ---------- MFMA GEMM (m97 structure): C[M,N] = A@W^T (+A2@W2^T) (+bias)(gelu?)(+resid) ----------
// 128x128 block tile, 4 waves of 64x64, BK=32, linear LDS + global_load_lds width 16,
// bijective XCD swizzle with m-panel-major flattening.
template<bool GELU, bool BF16OUT>
__global__ __launch_bounds__(256) void k_gemm(
    const unsigned short* __restrict__ A, const unsigned short* __restrict__ W,
    int M, int N, int K,
    const unsigned short* __restrict__ A2, const unsigned short* __restrict__ W2, int K2,
    const float* __restrict__ bias, const float* __restrict__ resid,
    void* __restrict__ Cout, int ldc, int gy)
{
    __shared__ unsigned short As[128][32];
    __shared__ unsigned short Ws[128][32];
    int tid = threadIdx.x;

    // XCD-aware bijective remap (m204 formula); m-major flat id -> n-tiles of one
    // A-panel are consecutive -> same XCD L2.
    int nwg = gridDim.x;
    int orig = blockIdx.x;
    int xcd = orig & 7, lid = orig >> 3;
    int q = nwg >> 3, r = nwg & 7;
    int wg = (xcd < r ? xcd * (q + 1) : r * (q + 1) + (xcd - r) * q) + lid;
    int bm128 = (wg / gy) * 128;
    int bn128 = (wg % gy) * 128;

    int l = tid & 63, w = tid >> 6;
    int wr = w >> 1, wc = w & 1;
    int lr = l & 15, lk = (l >> 4) * 8;
    int srow = l >> 2;            // staging row within 16-row chunk
    int sslot = (l & 3) * 8;      // staging element offset (8 bf16 = 16B)

    f32x4 acc[4][4];
    #pragma unroll
    for (int m = 0; m < 4; ++m)
        #pragma unroll
        for (int n = 0; n < 4; ++n) acc[m][n] = (f32x4){0.f, 0.f, 0.f, 0.f};

    auto kloop = [&](const unsigned short* __restrict__ Ap,
                     const unsigned short* __restrict__ Wp, int Kc) {
        for (int k0 = 0; k0 < Kc; k0 += 32) {
            #pragma unroll
            for (int i = 0; i < 2; ++i) {
                int row = w * 32 + i * 16 + srow;
                int ra = bm128 + row; if (ra >= M) ra = M - 1;   // clamp: feeds dead rows only
                async16((char*)&As[0][0] + w * 2048 + i * 1024,
                        Ap + (size_t)ra * Kc + k0 + sslot);
                int rb = bn128 + row; if (rb >= N) rb = N - 1;   // clamp: feeds dead cols only
                async16((char*)&Ws[0][0] + w * 2048 + i * 1024,
                        Wp + (size_t)rb * Kc + k0 + sslot);
            }
            __syncthreads();   // drains vmcnt(0): loads landed
            bf16x8 af[4], bfr[4];
            #pragma unroll
            for (int m = 0; m < 4; ++m) af[m] = *(const bf16x8*)&As[wr * 64 + m * 16 + lr][lk];
            #pragma unroll
            for (int n = 0; n < 4; ++n) bfr[n] = *(const bf16x8*)&Ws[wc * 64 + n * 16 + lr][lk];
            #pragma unroll
            for (int m = 0; m < 4; ++m)
                #pragma unroll
                for (int n = 0; n < 4; ++n)
                    acc[m][n] = __builtin_amdgcn_mfma_f32_16x16x32_bf16(af[m], bfr[n], acc[m][n], 0, 0, 0);
            __syncthreads();   // all waves done reading before next stage
        }
    };
    kloop(A, W, K);
    if (A2) kloop(A2, W2, K2);

    int rb0 = bm128 + wr * 64;
    int cb0 = bn128 + wc * 64;
    #pragma unroll
    for (int n = 0; n < 4; ++n) {
        int col = cb0 + n * 16 + lr;
        if (col >= N) continue;
        float bv = bias ? bias[col] : 0.0f;
        #pragma unroll
        for (int m = 0; m < 4; ++m) {
            #pragma unroll
            for (int rr = 0; rr < 4; ++rr) {
                int row = rb0 + m * 16 + (l >> 4) * 4 + rr;
                if (row >= M) continue;
                float c = acc[m][n][rr] + bv;
                if (GELU) c = gelu_exact(c);
                if (resid) c += resid[(size_t)row * ldc + col];
                if (BF16OUT) ((unsigned short*)Cout)[(size_t)row * ldc + col] = f2bf(c);
                else ((float*)Cout)[(size_t)row * ldc + col] = c;
            }
        }
    }
}

// ---------- flash attention: one block per (b*h, 64-row q tile) ----------
__global__ __launch_bounds__(256) void k_attn(const unsigned short* __restrict__ qkv,
                                              unsigned short* __restrict__ ctx) {
    int bh = blockIdx.x;
    int qt = blockIdx.y;
    int b = bh >> 4, h = bh & 15;
    int tid = threadIdx.x;
    int l = tid & 63;
    int w = tid >> 6;
    int lr = l & 15;
    int lk = (l >> 4) * 8;

    __shared__ unsigned short Qs[64][72];
    __shared__ unsigned short Ks[64][72];
    __shared__ unsigned short Vt[64][72];
    __shared__ unsigned short Ps[64][72];

    const size_t base = (size_t)b * NSEQ * NQKV + (size_t)h * 64;
    int q0 = qt * 64;

    {   // stage Q, pre-scaled by HD^-0.5 = 0.125 (exact pow2)
        int row = tid >> 2, ds = (tid & 3) * 16;
        int qrow = q0 + row;
        if (qrow < NSEQ) {
            const unsigned short* src = qkv + base + (size_t)qrow * NQKV + ds;
            #pragma unroll
            for (int j = 0; j < 16; ++j) Qs[row][ds + j] = f2bf(bf2f(src[j]) * 0.125f);
        } else {
            #pragma unroll
            for (int j = 0; j < 16; ++j) Qs[row][ds + j] = 0;
        }
    }

    float m_run[4], l_run[4];
    f32x4 o[4];
    #pragma unroll
    for (int r = 0; r < 4; ++r) { m_run[r] = -1e30f; l_run[r] = 0.0f; }
    #pragma unroll
    for (int n = 0; n < 4; ++n) o[n] = (f32x4){0.f, 0.f, 0.f, 0.f};

    for (int kt = 0; kt < 10; ++kt) {
        __syncthreads();
        {   // stage K (row-major) and V (transposed) tiles
            int row = tid >> 2, ds = (tid & 3) * 16;
            int key = kt * 64 + row;
            if (key < NSEQ) {
                const unsigned short* ksrc = qkv + base + (size_t)key * NQKV + 1024 + ds;
                *(ushort8*)&Ks[row][ds] = *(const ushort8*)ksrc;
                *(ushort8*)&Ks[row][ds + 8] = *(const ushort8*)(ksrc + 8);
                const unsigned short* vsrc = qkv + base + (size_t)key * NQKV + 2048 + ds;
                #pragma unroll
                for (int j = 0; j < 16; ++j) Vt[ds + j][row] = vsrc[j];
            } else {
                ushort8 z = {};
                *(ushort8*)&Ks[row][ds] = z;
                *(ushort8*)&Ks[row][ds + 8] = z;
                #pragma unroll
                for (int j = 0; j < 16; ++j) Vt[ds + j][row] = 0;
            }
        }
        __syncthreads();

        // S = Q @ K^T  (each wave: 16 q rows x 64 keys)
        f32x4 s[4];
        #pragma unroll
        for (int n = 0; n < 4; ++n) s[n] = (f32x4){0.f, 0.f, 0.f, 0.f};
        #pragma unroll
        for (int ks = 0; ks < 2; ++ks) {
            bf16x8 qa = *(const bf16x8*)&Qs[w * 16 + lr][ks * 32 + lk];
            #pragma unroll
            for (int n = 0; n < 4; ++n) {
                bf16x8 kb = *(const bf16x8*)&Ks[n * 16 + lr][ks * 32 + lk];
                s[n] = __builtin_amdgcn_mfma_f32_16x16x32_bf16(qa, kb, s[n], 0, 0, 0);
            }
        }
        // mask invalid keys
        #pragma unroll
        for (int n = 0; n < 4; ++n) {
            int col = kt * 64 + n * 16 + lr;
            if (col >= NSEQ) {
                #pragma unroll
                for (int r = 0; r < 4; ++r) s[n][r] = -1e30f;
            }
        }
        // online softmax (rows live across 16 lanes; xor-reduce within group)
        float tmax[4];
        #pragma unroll
        for (int r = 0; r < 4; ++r)
            tmax[r] = fmaxf(fmaxf(s[0][r], s[1][r]), fmaxf(s[2][r], s[3][r]));
        #pragma unroll
        for (int off = 1; off < 16; off <<= 1) {
            #pragma unroll
            for (int r = 0; r < 4; ++r) tmax[r] = fmaxf(tmax[r], __shfl_xor(tmax[r], off));
        }
        float alpha[4], rs[4];
        #pragma unroll
        for (int r = 0; r < 4; ++r) {
            float mn = fmaxf(m_run[r], tmax[r]);
            alpha[r] = __expf(m_run[r] - mn);
            m_run[r] = mn;
            rs[r] = 0.0f;
        }
        #pragma unroll
        for (int n = 0; n < 4; ++n) {
            #pragma unroll
            for (int r = 0; r < 4; ++r) {
                float p = __expf(s[n][r] - m_run[r]);
                s[n][r] = p;
                rs[r] += p;
            }
        }
        #pragma unroll
        for (int off = 1; off < 16; off <<= 1) {
            #pragma unroll
            for (int r = 0; r < 4; ++r) rs[r] += __shfl_xor(rs[r], off);
        }
        #pragma unroll
        for (int r = 0; r < 4; ++r) l_run[r] = l_run[r] * alpha[r] + rs[r];
        #pragma unroll
        for (int n = 0; n < 4; ++n) {
            #pragma unroll
            for (int r = 0; r < 4; ++r) o[n][r] *= alpha[r];
        }
        // P -> LDS (bf16), then O += P @ V
        #pragma unroll
        for (int n = 0; n < 4; ++n) {
            #pragma unroll
            for (int r = 0; r < 4; ++r)
                Ps[w * 16 + (l >> 4) * 4 + r][n * 16 + lr] = f2bf(s[n][r]);
        }
        __syncthreads();
        #pragma unroll
        for (int ks = 0; ks < 2; ++ks) {
            bf16x8 pa = *(const bf16x8*)&Ps[w * 16 + lr][ks * 32 + lk];
            #pragma unroll
            for (int n = 0; n < 4; ++n) {
                bf16x8 vb = *(const bf16x8*)&Vt[n * 16 + lr][ks * 32 + lk];
                o[n] = __builtin_amdgcn_mfma_f32_16x16x32_bf16(pa, vb, o[n], 0, 0, 0);
            }
        }
    }
    #pragma unroll
    for (int r = 0; r < 4; ++r) {
        int qrow = q0 + w * 16 + (l >> 4) * 4 + r;
        if (qrow < NSEQ) {
            float inv = (l_run[r] > 0.f) ? 1.0f / l_run[r] : 0.0f;
            #pragma unroll
            for (int n = 0; n < 4; ++n)
                ctx[((size_t)b * NSEQ + qrow) * EMB + h * 64 + n * 16 + lr] = f2bf(o[n][r] * inv);
        }
    }
}

extern "C" void kernel_launch(void* const* d_in, const int* in_sizes, int n_in,
                              void* d_out, int out_size, void* d_ws, size_t ws_size,
                              hipStream_t stream) {
    const float* tokens      = (const float*)d_in[0];
    const float* ln1_g       = (const float*)d_in[1];
    const float* ln1_b       = (const float*)d_in[2];
    const float* qkv_w       = (const float*)d_in[3];
    const float* qkv_b       = (const float*)d_in[4];
    const float* proj_w      = (const float*)d_in[5];
    const float* proj_b      = (const float*)d_in[6];
    const float* lora_gate_w = (const float*)d_in[7];
    const float* lora_A      = (const float*)d_in[8];
    const float* lora_B      = (const float*)d_in[9];
    const float* ln2_g       = (const float*)d_in[10];
    const float* ln2_b       = (const float*)d_in[11];
    const float* fc1_w       = (const float*)d_in[12];
    const float* fc1_b       = (const float*)d_in[13];
    const float* fc2_w       = (const float*)d_in[14];
    const float* fc2_b       = (const float*)d_in[15];
    const float* ad_gate_w   = (const float*)d_in[16];
    const float* ad_down_w   = (const float*)d_in[17];
    const float* ad_down_b   = (const float*)d_in[18];
    const float* ad_up_w     = (const float*)d_in[19];
    const float* ad_up_b     = (const float*)d_in[20];

    char* ws = (char*)d_ws;
    size_t off = 0;
    auto alloc = [&](size_t bytes) -> void* {
        void* p = ws + off;
        off += (bytes + 255) & ~(size_t)255;
        return p;
    };

    unsigned short* w_qkv  = (unsigned short*)alloc((size_t)NQKV * EMB * 2);
    unsigned short* w_proj = (unsigned short*)alloc((size_t)EMB * EMB * 2);
    unsigned short* w_fc1  = (unsigned short*)alloc((size_t)FFD * EMB * 2);
    unsigned short* w_fc2  = (unsigned short*)alloc((size_t)EMB * FFD * 2);
    unsigned short* w_acat = (unsigned short*)alloc((size_t)64 * EMB * 2);
    unsigned short* w_bcat = (unsigned short*)alloc((size_t)NQKV * 64 * 2);
    unsigned short* w_dcat = (unsigned short*)alloc((size_t)256 * EMB * 2);
    unsigned short* w_u    = (unsigned short*)alloc((size_t)EMB * 256 * 2);

    unsigned short* u1 = (unsigned short*)alloc((size_t)TOK * EMB * 2);  // normed -> mlpin
    char*           u2 = (char*)alloc((size_t)TOK * EMB * 2);            // ctx -> {ahpre, ahw}
    unsigned short* u3 = (unsigned short*)alloc((size_t)TOK * FFD * 2);  // qkv -> h1
    float* tok2   = (float*)alloc((size_t)TOK * EMB * 4);
    float* lora_h = (float*)alloc((size_t)TOK * 64 * 4);
    unsigned short* hw = (unsigned short*)alloc((size_t)TOK * 64 * 2);
    float* gates = (float*)alloc((size_t)TOK * 4 * 4);
    float* ag    = (float*)alloc((size_t)TOK * 4 * 4);

    unsigned short* normed = u1;
    unsigned short* mlpin  = u1;
    unsigned short* ctx    = (unsigned short*)u2;
    float*          ahpre  = (float*)u2;
    unsigned short* ahw    = (unsigned short*)(u2 + (size_t)TOK * 256 * 4);
    unsigned short* qkv    = u3;
    unsigned short* h1     = u3;

    // ---- weight conversion / packing ----
    k_f32_to_bf16<<<(NQKV * EMB + 255) / 256, 256, 0, stream>>>(qkv_w, w_qkv, NQKV * EMB);
    k_f32_to_bf16<<<(EMB * EMB + 255) / 256, 256, 0, stream>>>(proj_w, w_proj, EMB * EMB);
    k_f32_to_bf16<<<(FFD * EMB + 255) / 256, 256, 0, stream>>>(fc1_w, w_fc1, FFD * EMB);
    k_f32_to_bf16<<<(EMB * FFD + 255) / 256, 256, 0, stream>>>(fc2_w, w_fc2, EMB * FFD);
    k_f32_to_bf16<<<(64 * EMB + 255) / 256, 256, 0, stream>>>(lora_A, w_acat, 64 * EMB);
    k_pack_bcat<<<(NQKV * 64 + 255) / 256, 256, 0, stream>>>(lora_B, w_bcat);
    k_f32_to_bf16<<<(256 * EMB + 255) / 256, 256, 0, stream>>>(ad_down_w, w_dcat, 256 * EMB);
    k_pack_u<<<(EMB * 256 + 255) / 256, 256, 0, stream>>>(ad_up_w, w_u);

    // ---- forward ----
    k_ln_gates<<<TOK, 256, 0, stream>>>(tokens, ln1_g, ln1_b, lora_gate_w, normed, gates);
    k_gemm<false, false><<<73 * 1, 256, 0, stream>>>(
        normed, w_acat, TOK, 64, EMB, nullptr, nullptr, 0, nullptr, nullptr, lora_h, 64, 1);
    k_make_hw<<<(TOK * 64 + 255) / 256, 256, 0, stream>>>(gates, lora_h, hw);
    k_gemm<false, true><<<73 * 24, 256, 0, stream>>>(
        normed, w_qkv, TOK, NQKV, EMB, hw, w_bcat, 64, qkv_b, nullptr, qkv, NQKV, 24);
    k_attn<<<dim3(256, 10), 256, 0, stream>>>(qkv, ctx);
    k_gemm<false, false><<<73 * 8, 256, 0, stream>>>(
        ctx, w_proj, TOK, EMB, EMB, nullptr, nullptr, 0, proj_b, tokens, tok2, EMB, 8);
    k_ln_gates<<<TOK, 256, 0, stream>>>(tok2, ln2_g, ln2_b, ad_gate_w, mlpin, ag);
    k_gemm<false, false><<<73 * 2, 256, 0, stream>>>(
        mlpin, w_dcat, TOK, 256, EMB, nullptr, nullptr, 0, ad_down_b, nullptr, ahpre, 256, 2);
    k_make_ahw<<<(TOK * 256 + 255) / 256, 256, 0, stream>>>(ag, ahpre, ahw);
    k_adbias<<<TOK, 256, 0, stream>>>(ag, ad_up_b, tok2);
    k_gemm<true, true><<<73 * 32, 256, 0, stream>>>(
        mlpin, w_fc1, TOK, FFD, EMB, nullptr, nullptr, 0, fc1_b, nullptr, h1, FFD, 32);
    k_gemm<false, false><<<73 * 8, 256, 0, stream>>>(
        h1, w_fc2, TOK, EMB, FFD, ahw, w_u, 256, fc2_b, tok2, d_out, EMB, 8);
}